// Round 8
// baseline (108.685 us; speedup 1.0000x reference)
//
#include <hip/hip_runtime.h>

// Problem: TemporalAttention_54322746359850
// Identity: softmax rows sum to 1 and einsum('TNS,BNH->BNH') contracts attn over
// BOTH T and S => y == 1024*v exactly; adjacency/QK/softmax are dead code.
//   att    = (1024*(h_pred@Wv + bv)) @ Wo + bo
//   gate   = sigmoid( silu([h_pred,h_prev]@gW1 + gb1) @ gW2 + gb2 )
//   h_corr = h_prev + gate*att
//   out    = h_corr + relu([h_corr,h_prev]@mW1 + mb1) @ mW2 + mb2
// Inputs f32, output f32 (verified R2/R3/R4).
//
// R7 post-mortem: prefetch+rotation neutral; 1 block/CU means all waves share
// every barrier drain -> correlated stall is the bottleneck. This version:
// 2 independent blocks per CU (grid 512 x block 512, ROWS=2), <=128 VGPR
// (single-buffered weights, early-issued one barrier ahead), 16 waves/CU in
// two barrier domains that interleave.

#define HH 128
#define NROWS 1024
#define ROWS 2      // rows per block
#define NT 512      // threads per block (8 waves)
#define NG 16       // c-groups (8 K-rows each per 128-K)

__device__ __forceinline__ void fma4(float4& a, float s, const float4& w) {
    a.x += s * w.x; a.y += s * w.y; a.z += s * w.z; a.w += s * w.w;
}

__global__ __launch_bounds__(NT, 4) void temporal_attn_fused(
    const float* __restrict__ h_prev,
    const float* __restrict__ h_pred,
    const float* __restrict__ Wv, const float* __restrict__ bv,
    const float* __restrict__ Wo, const float* __restrict__ bo,
    const float* __restrict__ gW1, const float* __restrict__ gb1,
    const float* __restrict__ gW2, const float* __restrict__ gb2,
    const float* __restrict__ mW1, const float* __restrict__ mb1,
    const float* __restrict__ mW2, const float* __restrict__ mb2,
    float* __restrict__ out)
{
    __shared__ __align__(16) float sPred[ROWS][HH];
    __shared__ __align__(16) float sPrev[ROWS][HH];
    __shared__ __align__(16) float sBuf[ROWS][HH];   // a, then g1, then m1
    __shared__ __align__(16) float sCorr[ROWS][HH];
    __shared__ __align__(16) float sAtt[ROWS][HH];
    __shared__ float4 part4[NG][ROWS][HH / 4];       // 16 KB partials

    const int tid = threadIdx.x;
    const int jq  = tid & 31;                        // j-quad: cols 4*jq..4*jq+3
    const int cg  = ((tid >> 5) + blockIdx.x) & 15;  // rotated c-group
    const int rr  = tid >> 7;                        // 0..3 (rows valid: 0..1)
    const int jj  = tid & (HH - 1);                  // col 0..127
    const int r0  = blockIdx.x * ROWS;

    // ---- stage activations (rows 0..1 handled by threads 0..255) ----
    if (rr < ROWS) {
        sPred[rr][jj] = h_pred[(r0 + rr) * HH + jj];
        sPrev[rr][jj] = h_prev[(r0 + rr) * HH + jj];
    }
    const float rbv  = bv[jj],  rbo  = bo[jj];
    const float rgb1 = gb1[jj], rgb2 = gb2[jj];
    const float rmb1 = mb1[jj], rmb2 = mb2[jj];
    __syncthreads();

    const float* pf = (const float*)part4;
    const int cbase = rr * HH + jj;                  // combine read base (dwords)

    float4 w[16];
    float4 acc[ROWS];

    // weight loads: this thread's 8 (or 16) K-rows, its col-quad
    #define LOAD_W128(W) { \
        const float4* W4 = (const float4*)(W); \
        _Pragma("unroll") for (int i = 0; i < 8; ++i) \
            w[i] = W4[(8 * cg + i) * (HH / 4) + jq]; }

    #define LOAD_W256(W) { \
        const float4* W4 = (const float4*)(W); \
        _Pragma("unroll") for (int i = 0; i < 8; ++i) { \
            w[i]     = W4[(8 * cg + i) * (HH / 4) + jq]; \
            w[8 + i] = W4[(HH + 8 * cg + i) * (HH / 4) + jq]; } }

    #define FMA128(S) { \
        _Pragma("unroll") for (int r = 0; r < ROWS; ++r) { \
            acc[r] = make_float4(0.f, 0.f, 0.f, 0.f); \
            float4 a0 = *(const float4*)&S[r][8 * cg]; \
            float4 a1 = *(const float4*)&S[r][8 * cg + 4]; \
            fma4(acc[r], a0.x, w[0]); fma4(acc[r], a0.y, w[1]); \
            fma4(acc[r], a0.z, w[2]); fma4(acc[r], a0.w, w[3]); \
            fma4(acc[r], a1.x, w[4]); fma4(acc[r], a1.y, w[5]); \
            fma4(acc[r], a1.z, w[6]); fma4(acc[r], a1.w, w[7]); } }

    #define FMA256(SA, SB) { \
        _Pragma("unroll") for (int r = 0; r < ROWS; ++r) { \
            acc[r] = make_float4(0.f, 0.f, 0.f, 0.f); \
            float4 a0 = *(const float4*)&SA[r][8 * cg]; \
            float4 a1 = *(const float4*)&SA[r][8 * cg + 4]; \
            float4 b0 = *(const float4*)&SB[r][8 * cg]; \
            float4 b1 = *(const float4*)&SB[r][8 * cg + 4]; \
            fma4(acc[r], a0.x, w[0]);  fma4(acc[r], a0.y, w[1]); \
            fma4(acc[r], a0.z, w[2]);  fma4(acc[r], a0.w, w[3]); \
            fma4(acc[r], a1.x, w[4]);  fma4(acc[r], a1.y, w[5]); \
            fma4(acc[r], a1.z, w[6]);  fma4(acc[r], a1.w, w[7]); \
            fma4(acc[r], b0.x, w[8]);  fma4(acc[r], b0.y, w[9]); \
            fma4(acc[r], b0.z, w[10]); fma4(acc[r], b0.w, w[11]); \
            fma4(acc[r], b1.x, w[12]); fma4(acc[r], b1.y, w[13]); \
            fma4(acc[r], b1.z, w[14]); fma4(acc[r], b1.w, w[15]); } }

    #define PSTORE() { \
        _Pragma("unroll") for (int r = 0; r < ROWS; ++r) part4[cg][r][jq] = acc[r]; \
        __syncthreads(); }

    #define COMBINE(dotvar) \
        float dotvar = 0.f; \
        _Pragma("unroll") for (int g = 0; g < NG; ++g) dotvar += pf[g * (ROWS * HH) + cbase];

    // ---- step 1: a = 1024*(h_pred @ Wv + bv) -> sBuf ----
    LOAD_W128(Wv);
    FMA128(sPred);
    LOAD_W128(Wo);              // early-issue step 2 (w consumed above)
    PSTORE();
    if (rr < ROWS) { COMBINE(dot); sBuf[rr][jj] = 1024.f * (dot + rbv); }
    __syncthreads();

    // ---- step 2: att = a @ Wo + bo -> sAtt ----
    FMA128(sBuf);
    LOAD_W256(gW1);             // early-issue step 3
    PSTORE();
    if (rr < ROWS) { COMBINE(dot); sAtt[rr][jj] = dot + rbo; }
    __syncthreads();

    // ---- step 3: g1 = silu([h_pred,h_prev] @ gW1 + gb1) -> sBuf ----
    FMA256(sPred, sPrev);
    LOAD_W128(gW2);             // early-issue step 4
    PSTORE();
    if (rr < ROWS) { COMBINE(dot);
        float x = dot + rgb1;
        sBuf[rr][jj] = x / (1.f + __expf(-x)); }
    __syncthreads();

    // ---- step 4: gate = sigmoid(g1 @ gW2 + gb2); h_corr = h_prev + gate*att ----
    FMA128(sBuf);
    LOAD_W256(mW1);             // early-issue step 5
    PSTORE();
    if (rr < ROWS) { COMBINE(dot);
        float gate = 1.f / (1.f + __expf(-(dot + rgb2)));
        sCorr[rr][jj] = sPrev[rr][jj] + gate * sAtt[rr][jj]; }
    __syncthreads();

    // ---- step 5: m1 = relu([h_corr,h_prev] @ mW1 + mb1) -> sBuf ----
    FMA256(sCorr, sPrev);
    LOAD_W128(mW2);             // early-issue step 6
    PSTORE();
    if (rr < ROWS) { COMBINE(dot); sBuf[rr][jj] = fmaxf(dot + rmb1, 0.f); }
    __syncthreads();

    // ---- step 6: out = h_corr + m1 @ mW2 + mb2 ----
    FMA128(sBuf);
    PSTORE();
    if (rr < ROWS) { COMBINE(dot); out[(r0 + rr) * HH + jj] = sCorr[rr][jj] + dot + rmb2; }
}

extern "C" void kernel_launch(void* const* d_in, const int* in_sizes, int n_in,
                              void* d_out, int out_size, void* d_ws, size_t ws_size,
                              hipStream_t stream) {
    // setup_inputs order:
    // 0 h_prev, 1 h_pred, 2 adj_rows, 3 adj_cols,
    // 4 Wq, 5 bq, 6 Wk, 7 bk, 8 Wv, 9 bv, 10 Wo, 11 bo,
    // 12 gW1, 13 gb1, 14 gW2, 15 gb2, 16 mW1, 17 mb1, 18 mW2, 19 mb2
    const float* h_prev = (const float*)d_in[0];
    const float* h_pred = (const float*)d_in[1];
    const float* Wv  = (const float*)d_in[8];
    const float* bv  = (const float*)d_in[9];
    const float* Wo  = (const float*)d_in[10];
    const float* bo  = (const float*)d_in[11];
    const float* gW1 = (const float*)d_in[12];
    const float* gb1 = (const float*)d_in[13];
    const float* gW2 = (const float*)d_in[14];
    const float* gb2 = (const float*)d_in[15];
    const float* mW1 = (const float*)d_in[16];
    const float* mb1 = (const float*)d_in[17];
    const float* mW2 = (const float*)d_in[18];
    const float* mb2 = (const float*)d_in[19];
    float* out = (float*)d_out;

    dim3 grid(NROWS / ROWS);   // 512 blocks -> 2 per CU
    dim3 block(NT);            // 512 threads = 8 waves
    hipLaunchKernelGGL(temporal_attn_fused, grid, block, 0, stream,
                       h_prev, h_pred, Wv, bv, Wo, bo,
                       gW1, gb1, gW2, gb2, mW1, mb1, mW2, mb2, out);
}

// Round 9
// 103.873 us; speedup vs baseline: 1.0463x; 1.0463x over previous
//
#include <hip/hip_runtime.h>

// Problem: TemporalAttention_54322746359850
// Identity: softmax rows sum to 1 and einsum('TNS,BNH->BNH') contracts attn over
// BOTH T and S => y == 1024*v exactly; adjacency/QK/softmax are dead code.
//   att    = (1024*(h_pred@Wv + bv)) @ Wo + bo
//   gate   = sigmoid( silu([h_pred,h_prev]@gW1 + gb1) @ gW2 + gb2 )
//   h_corr = h_prev + gate*att
//   out    = h_corr + relu([h_corr,h_prev]@mW1 + mb1) @ mW2 + mb2
// Inputs f32, output f32 (verified R2/R3/R4).
//
// R8 post-mortem: traffic scales with blocks x 512KB weight set; 512 blocks
// (268MB) regressed vs 256 (134MB). Column-split impossible (chain needs full
// rows). This version halves traffic: ROWS=8, grid=128 (67MB). Thread =
// (cg 0..7) x (row-half 0..1) x (col-quad 0..31); 4 rows x 4 cols each;
// K=256 steps reuse the 16 weight regs in two batches.

#define HH 128
#define NROWS 1024
#define ROWS 8      // rows per block
#define NT 512      // threads per block (8 waves)
#define NG 8        // K-groups (16 K-rows each per 128-K)

__device__ __forceinline__ void fma4(float4& a, float s, const float4& w) {
    a.x += s * w.x; a.y += s * w.y; a.z += s * w.z; a.w += s * w.w;
}

__global__ __launch_bounds__(NT) void temporal_attn_fused(
    const float* __restrict__ h_prev,
    const float* __restrict__ h_pred,
    const float* __restrict__ Wv, const float* __restrict__ bv,
    const float* __restrict__ Wo, const float* __restrict__ bo,
    const float* __restrict__ gW1, const float* __restrict__ gb1,
    const float* __restrict__ gW2, const float* __restrict__ gb2,
    const float* __restrict__ mW1, const float* __restrict__ mb1,
    const float* __restrict__ mW2, const float* __restrict__ mb2,
    float* __restrict__ out)
{
    __shared__ __align__(16) float sPred[ROWS][HH];
    __shared__ __align__(16) float sPrev[ROWS][HH];
    __shared__ __align__(16) float sBuf[ROWS][HH];   // a, then g1, then m1
    __shared__ __align__(16) float sCorr[ROWS][HH];
    __shared__ __align__(16) float sAtt[ROWS][HH];
    __shared__ float4 part4[NG][ROWS][HH / 4];       // 32 KB partials

    const int tid = threadIdx.x;
    const int jq  = tid & 31;                        // col-quad: cols 4*jq..4*jq+3
    const int rh  = (tid >> 5) & 1;                  // row-half: rows 4*rh..4*rh+3
    const int cg  = ((tid >> 6) + blockIdx.x) & 7;   // rotated K-group: K-rows 16*cg..16*cg+15
    const int e0  = tid >> 7;                        // epilogue row a (0..3); row b = e0+4
    const int jj  = tid & (HH - 1);                  // epilogue col 0..127
    const int r0  = blockIdx.x * ROWS;

    // ---- stage activations: thread loads (e0,jj) and (e0+4,jj) ----
    sPred[e0][jj]     = h_pred[(r0 + e0) * HH + jj];
    sPred[e0 + 4][jj] = h_pred[(r0 + e0 + 4) * HH + jj];
    sPrev[e0][jj]     = h_prev[(r0 + e0) * HH + jj];
    sPrev[e0 + 4][jj] = h_prev[(r0 + e0 + 4) * HH + jj];
    const float rbv  = bv[jj],  rbo  = bo[jj];
    const float rgb1 = gb1[jj], rgb2 = gb2[jj];
    const float rmb1 = mb1[jj], rmb2 = mb2[jj];
    __syncthreads();

    const float* pf = (const float*)part4;

    float4 w[16];
    float4 acc[4];

    // load this thread's 16 K-rows x col-quad of a 128x128 weight block
    #define LOAD_W(W) { \
        const float4* W4 = (const float4*)(W); \
        _Pragma("unroll") for (int i = 0; i < 16; ++i) \
            w[i] = W4[(16 * cg + i) * (HH / 4) + jq]; }

    #define ZERO_ACC() { \
        _Pragma("unroll") for (int r = 0; r < 4; ++r) \
            acc[r] = make_float4(0.f, 0.f, 0.f, 0.f); }

    // accumulate 4 rows x 4 cols over this thread's 16 K-rows from act S
    #define FMA_ACC(S) { \
        _Pragma("unroll") for (int r = 0; r < 4; ++r) { \
            const int row = 4 * rh + r; \
            float4 a0 = *(const float4*)&S[row][16 * cg]; \
            float4 a1 = *(const float4*)&S[row][16 * cg + 4]; \
            float4 a2 = *(const float4*)&S[row][16 * cg + 8]; \
            float4 a3 = *(const float4*)&S[row][16 * cg + 12]; \
            fma4(acc[r], a0.x, w[0]);  fma4(acc[r], a0.y, w[1]); \
            fma4(acc[r], a0.z, w[2]);  fma4(acc[r], a0.w, w[3]); \
            fma4(acc[r], a1.x, w[4]);  fma4(acc[r], a1.y, w[5]); \
            fma4(acc[r], a1.z, w[6]);  fma4(acc[r], a1.w, w[7]); \
            fma4(acc[r], a2.x, w[8]);  fma4(acc[r], a2.y, w[9]); \
            fma4(acc[r], a2.z, w[10]); fma4(acc[r], a2.w, w[11]); \
            fma4(acc[r], a3.x, w[12]); fma4(acc[r], a3.y, w[13]); \
            fma4(acc[r], a3.z, w[14]); fma4(acc[r], a3.w, w[15]); } }

    #define PSTORE() { \
        _Pragma("unroll") for (int r = 0; r < 4; ++r) \
            part4[cg][4 * rh + r][jq] = acc[r]; \
        __syncthreads(); }

    // combine partials for (row, jj): sum over 8 K-groups
    #define COMBINE(dotvar, row) \
        float dotvar = 0.f; \
        _Pragma("unroll") for (int g = 0; g < NG; ++g) \
            dotvar += pf[(g * ROWS + (row)) * HH + jj];

    // ---- step 1: a = 1024*(h_pred @ Wv + bv) -> sBuf ----
    ZERO_ACC(); LOAD_W(Wv); FMA_ACC(sPred); PSTORE();
    { COMBINE(d0, e0); COMBINE(d1, e0 + 4);
      sBuf[e0][jj]     = 1024.f * (d0 + rbv);
      sBuf[e0 + 4][jj] = 1024.f * (d1 + rbv); }
    __syncthreads();

    // ---- step 2: att = a @ Wo + bo -> sAtt ----
    ZERO_ACC(); LOAD_W(Wo); FMA_ACC(sBuf); PSTORE();
    { COMBINE(d0, e0); COMBINE(d1, e0 + 4);
      sAtt[e0][jj]     = d0 + rbo;
      sAtt[e0 + 4][jj] = d1 + rbo; }
    __syncthreads();

    // ---- step 3: g1 = silu([h_pred,h_prev] @ gW1 + gb1) -> sBuf ----
    ZERO_ACC();
    LOAD_W(gW1);           FMA_ACC(sPred);
    LOAD_W(gW1 + HH * HH); FMA_ACC(sPrev);
    PSTORE();
    { COMBINE(d0, e0); COMBINE(d1, e0 + 4);
      float x0 = d0 + rgb1, x1 = d1 + rgb1;
      sBuf[e0][jj]     = x0 / (1.f + __expf(-x0));
      sBuf[e0 + 4][jj] = x1 / (1.f + __expf(-x1)); }
    __syncthreads();

    // ---- step 4: gate = sigmoid(g1 @ gW2 + gb2); h_corr = h_prev + gate*att ----
    ZERO_ACC(); LOAD_W(gW2); FMA_ACC(sBuf); PSTORE();
    { COMBINE(d0, e0); COMBINE(d1, e0 + 4);
      float g0 = 1.f / (1.f + __expf(-(d0 + rgb2)));
      float g1 = 1.f / (1.f + __expf(-(d1 + rgb2)));
      sCorr[e0][jj]     = sPrev[e0][jj]     + g0 * sAtt[e0][jj];
      sCorr[e0 + 4][jj] = sPrev[e0 + 4][jj] + g1 * sAtt[e0 + 4][jj]; }
    __syncthreads();

    // ---- step 5: m1 = relu([h_corr,h_prev] @ mW1 + mb1) -> sBuf ----
    ZERO_ACC();
    LOAD_W(mW1);           FMA_ACC(sCorr);
    LOAD_W(mW1 + HH * HH); FMA_ACC(sPrev);
    PSTORE();
    { COMBINE(d0, e0); COMBINE(d1, e0 + 4);
      sBuf[e0][jj]     = fmaxf(d0 + rmb1, 0.f);
      sBuf[e0 + 4][jj] = fmaxf(d1 + rmb1, 0.f); }
    __syncthreads();

    // ---- step 6: out = h_corr + m1 @ mW2 + mb2 ----
    ZERO_ACC(); LOAD_W(mW2); FMA_ACC(sBuf); PSTORE();
    { COMBINE(d0, e0); COMBINE(d1, e0 + 4);
      out[(r0 + e0) * HH + jj]     = sCorr[e0][jj]     + d0 + rmb2;
      out[(r0 + e0 + 4) * HH + jj] = sCorr[e0 + 4][jj] + d1 + rmb2; }
}

extern "C" void kernel_launch(void* const* d_in, const int* in_sizes, int n_in,
                              void* d_out, int out_size, void* d_ws, size_t ws_size,
                              hipStream_t stream) {
    // setup_inputs order:
    // 0 h_prev, 1 h_pred, 2 adj_rows, 3 adj_cols,
    // 4 Wq, 5 bq, 6 Wk, 7 bk, 8 Wv, 9 bv, 10 Wo, 11 bo,
    // 12 gW1, 13 gb1, 14 gW2, 15 gb2, 16 mW1, 17 mb1, 18 mW2, 19 mb2
    const float* h_prev = (const float*)d_in[0];
    const float* h_pred = (const float*)d_in[1];
    const float* Wv  = (const float*)d_in[8];
    const float* bv  = (const float*)d_in[9];
    const float* Wo  = (const float*)d_in[10];
    const float* bo  = (const float*)d_in[11];
    const float* gW1 = (const float*)d_in[12];
    const float* gb1 = (const float*)d_in[13];
    const float* gW2 = (const float*)d_in[14];
    const float* gb2 = (const float*)d_in[15];
    const float* mW1 = (const float*)d_in[16];
    const float* mb1 = (const float*)d_in[17];
    const float* mW2 = (const float*)d_in[18];
    const float* mb2 = (const float*)d_in[19];
    float* out = (float*)d_out;

    dim3 grid(NROWS / ROWS);   // 128 blocks
    dim3 block(NT);            // 512 threads = 8 waves
    hipLaunchKernelGGL(temporal_attn_fused, grid, block, 0, stream,
                       h_prev, h_pred, Wv, bv, Wo, bo,
                       gW1, gb1, gW2, gb2, mW1, mb1, mW2, mb2, out);
}